// Round 5
// baseline (90.024 us; speedup 1.0000x reference)
//
#include <hip/hip_runtime.h>

// ToeplitzMemoryProjection (HiPPO LagT, alpha=0.5 bilinear).
//
// Math: with c = 1 + 0.25*dt, g = (1-0.25*dt)/c, beta = dt*u/c, the step
// operator is (g*I - S)(I - g*S)^{-1} (S = down-shift) and the input term is
// beta*(I - g*S)^{-1} e0. Multiplying the scan x_l = A_l x_{l-1} + B_l by
// (I - g_l S) (exact in the truncated lower-tri Toeplitz algebra) gives the
// O(N)-per-step recurrence
//
//   x_l[i] = g_l*(x_l[i-1] + x_{l-1}[i]) - x_{l-1}[i-1] + beta_l*[i==0]
//
// Lane-skewed wavefront: 1 block per channel (256 ch), 256 threads (col = tid),
// thread i handles row l at tick T = l + wave*SKEW + lane.
//   - x_l[i-1] via DPP wave_shr:1 (VALU-latency lane shift, lane0 -> 0)
//   - cross-wave handoff: lane0 reads left wave's ring column 63 directly
//   - ring slots TICK-indexed (slot = t & 127, wave-uniform)
//   - ROUND-5 FIX: all per-chunk LDS reads are issued as VOLATILE INLINE-ASM
//     ds_read_b32 clusters followed by ONE s_waitcnt lgkmcnt(0) +
//     sched_barrier(0) (guide rule 18). Rounds 1-4 sat at ~85us because the
//     compiler (VGPR=24) re-interleaved every ds_read next to its use ->
//     ~96 serialized 120-cy LDS round-trips per chunk. Volatile asm reads
//     keep relative order and cannot be split, so each cluster costs
//     issue + one latency instead of 32 latencies.
//   - barriers are LDS-only (s_waitcnt lgkmcnt(0) + s_barrier, no vmcnt
//     drain): the nontemporal HBM store stream stays in flight across chunks.
//   - completed rows flushed as coalesced 256 B nontemporal row-segment stores

namespace {

constexpr int LLEN  = 1024;              // L
constexpr int NCHAN = 256;               // B*M
constexpr int NWAVE = 4;                 // waves per block (N = 256 cols)
constexpr int KCH   = 32;                // ticks per chunk (barrier period)
constexpr int SKEW  = 64 + KCH;          // per-wave tick offset (96); SKEW-63=33>KCH-1
constexpr int RINGT = 128;               // tick-indexed ring slots per wave (pow2)
constexpr int LAST_T = (LLEN - 1) + 255 + (NWAVE - 1) * KCH;  // 1374
constexpr int NCHUNK = LAST_T / KCH + 1; // 43

constexpr int G_OFF = 0;
constexpr int B_OFF = LLEN;
constexpr int R_OFF = 2 * LLEN;
constexpr int LDS_FLOATS = R_OFF + NWAVE * RINGT * 64;
constexpr size_t LDS_BYTES = (size_t)LDS_FLOATS * sizeof(float);  // 139264 B

__device__ __forceinline__ float dpp_wave_shr1(float v) {
    // v_mov_b32_dpp wave_shr:1 — lane i gets lane i-1's value, lane 0 gets `old`=0.
    return __int_as_float(__builtin_amdgcn_update_dpp(
        0, __float_as_int(v), 0x138 /*WAVE_SHR1*/, 0xF, 0xF, false));
}

// Low 32 bits of a generic pointer to LDS == DS byte address.
__device__ __forceinline__ unsigned lds_a(const void* p) {
    return (unsigned)(unsigned long long)p;
}

// Volatile asm LDS read: stays in program order relative to other volatile
// asm; a cluster of these issues back-to-back (pipelined in the LDS queue).
__device__ __forceinline__ void ds_read_f32(float& dst, unsigned addr) {
    asm volatile("ds_read_b32 %0, %1" : "=v"(dst) : "v"(addr));
}

// Single wait for a read cluster + scheduler fence (guide rule 18).
__device__ __forceinline__ void wait_lgkm0_fence() {
    asm volatile("s_waitcnt lgkmcnt(0)" ::: "memory");
    __builtin_amdgcn_sched_barrier(0);
}

// Compiler-level memory ordering fence (keeps C ds_writes before asm reads).
__device__ __forceinline__ void compiler_mem_fence() {
    asm volatile("" ::: "memory");
}

// LDS-only barrier: order ring ds_writes/ds_reads across waves WITHOUT
// draining the global store queue (vmcnt untouched).
__device__ __forceinline__ void lds_barrier() {
    __builtin_amdgcn_sched_barrier(0);
    asm volatile("s_waitcnt lgkmcnt(0)" ::: "memory");
    __builtin_amdgcn_s_barrier();
    __builtin_amdgcn_sched_barrier(0);
}

// One KCH-tick chunk. hb source: W0 -> b_arr (beta, lane0 adds it);
// else -> left wave's ring column 63 (handoff, lane0 adds it).
template <bool W0, bool MASKED>
__device__ __forceinline__ void do_chunk_asm(
    int T0, int base_l, int lane, bool lane0,
    unsigned g_base, unsigned hb_base,
    float* __restrict__ my_ring, float& prev_own, float& prev_left)
{
    float gpre[KCH], hbv[KCH];

    // ---- read cluster: 32 g + 32 handoff/beta, one wait ----
    if (MASKED) {
        #pragma unroll
        for (int s = 0; s < KCH; ++s) {
            const int l = min(max(base_l + s - lane, 0), LLEN - 1);
            ds_read_f32(gpre[s], g_base + 4u * (unsigned)l);
        }
    } else {
        unsigned a = g_base + 4u * (unsigned)(base_l - lane);
        #pragma unroll
        for (int s = 0; s < KCH; ++s) { ds_read_f32(gpre[s], a); a += 4u; }
    }
    #pragma unroll
    for (int s = 0; s < KCH; ++s) {
        if (W0) {
            const int t = MASKED ? min(T0 + s, LLEN - 1) : (T0 + s);
            ds_read_f32(hbv[s], hb_base + 4u * (unsigned)t);
        } else {
            // left wave lane-63 value for tick T0+s-33 (>=1 chunk old; slot
            // reuse distance 128 ticks >= 3 chunks). T0+s-33 >= 32 > 0 here.
            const unsigned slot = (unsigned)(T0 + s - (SKEW - 63)) & (RINGT - 1);
            ds_read_f32(hbv[s], hb_base + (slot << 8) + 63u * 4u);
        }
    }
    wait_lgkm0_fence();

    // ---- 32 ticks: serial dpp->fma chain, fire-and-forget ring writes ----
    const int rb = ((T0 & (RINGT - 1)) << 6) + lane;  // never wraps mid-chunk
    #pragma unroll
    for (int s = 0; s < KCH; ++s) {
        float cl = dpp_wave_shr1(prev_own);
        const float sel = lane0 ? hbv[s] : 0.0f;
        if (!W0) cl = cl + sel;                       // lane0: left-wave handoff
        const float cterm = W0 ? (sel - prev_left)    // lane0: +beta
                               : (0.0f - prev_left);
        const float x = fmaf(gpre[s], cl, fmaf(gpre[s], prev_own, cterm));
        my_ring[rb + (s << 6)] = x;                   // OOB-row garbage never flushed
        if (MASKED) {
            const int l = base_l + s - lane;
            const bool act = (l >= 0) & (l < LLEN);
            prev_left = act ? cl : prev_left;
            prev_own  = act ? x  : prev_own;
        } else {
            prev_left = cl;
            prev_own  = x;
        }
    }
}

__global__ __launch_bounds__(256, 1)
void toeplitz_scan(const float* __restrict__ vin,   // inputs (L, 256)
                   const float* __restrict__ dtin,  // dt     (L, 256)
                   float* __restrict__ out)         // (L, 256, 256)
{
    extern __shared__ float lds[];
    float* g_arr = lds + G_OFF;   // [LLEN]
    float* b_arr = lds + B_OFF;   // [LLEN]
    float* ring  = lds + R_OFF;   // [NWAVE][RINGT][64], tick-indexed slots

    const int ch   = blockIdx.x;
    const int tid  = threadIdx.x;
    const int wave = tid >> 6;
    const int lane = tid & 63;

    // ---- precompute g[l], beta[l] for this channel ----
    #pragma unroll
    for (int k = 0; k < LLEN / 256; ++k) {
        const int l = tid + k * 256;
        const float d = dtin[l * NCHAN + ch];
        const float u = vin[l * NCHAN + ch];
        const float inv_c = 1.0f / (1.0f + 0.25f * d);
        g_arr[l] = (1.0f - 0.25f * d) * inv_c;
        b_arr[l] = d * u * inv_c;
    }
    __syncthreads();

    float* my_ring = ring + wave * (RINGT * 64);
    const unsigned g_base  = lds_a(g_arr);
    const unsigned b_base  = lds_a(b_arr);
    const unsigned my_base = lds_a(my_ring);
    const unsigned lf_base = lds_a(ring + (wave - 1) * (RINGT * 64)); // wave>0

    const int wskew  = wave * SKEW;
    const bool w0    = (wave == 0);
    const bool lane0 = (lane == 0);

    float prev_own = 0.0f, prev_left = 0.0f;
    int nf = 0;                                   // next row to flush
    float* outp = out + (ch * 256 + wave * 64 + lane);  // +65536 per row

    for (int c = 0; c < NCHUNK; ++c) {
        const int T0 = c * KCH;
        const int base_l = T0 - wskew;            // lane0's row at s=0
        const bool any_act = (base_l >= -(KCH - 1)) && (base_l <= LLEN - 1 + 63);

        if (any_act) {
            const bool all_act = (base_l >= 63) && (base_l <= LLEN - KCH);
            const unsigned hb = w0 ? b_base : lf_base;
            if (w0) {
                if (all_act)
                    do_chunk_asm<true, false>(T0, base_l, lane, lane0,
                                              g_base, hb, my_ring, prev_own, prev_left);
                else
                    do_chunk_asm<true, true>(T0, base_l, lane, lane0,
                                             g_base, hb, my_ring, prev_own, prev_left);
            } else {
                if (all_act)
                    do_chunk_asm<false, false>(T0, base_l, lane, lane0,
                                               g_base, hb, my_ring, prev_own, prev_left);
                else
                    do_chunk_asm<false, true>(T0, base_l, lane, lane0,
                                              g_base, hb, my_ring, prev_own, prev_left);
            }
        }

        // ---- flush rows whose lane-63 value landed by tick T0+KCH-1 ----
        {
            const int hi = min(base_l + KCH - 64, LLEN - 1);
            if (hi - nf == KCH - 1) {             // steady state: exactly KCH rows
                compiler_mem_fence();             // ring ds_writes stay above
                float tmp[KCH];
                const unsigned fb = my_base + 4u * (unsigned)lane;
                const int t0f = nf + wskew + lane;
                #pragma unroll
                for (int q = 0; q < KCH; ++q) {
                    const unsigned slot = (unsigned)(t0f + q) & (RINGT - 1);
                    ds_read_f32(tmp[q], fb + (slot << 8));
                }
                wait_lgkm0_fence();
                #pragma unroll
                for (int q = 0; q < KCH; ++q) {
                    __builtin_nontemporal_store(tmp[q], outp);
                    outp += NCHAN * 256;
                }
                nf += KCH;
            } else {
                for (; nf <= hi; ++nf) {
                    const int slot = (nf + wskew + lane) & (RINGT - 1);
                    __builtin_nontemporal_store(my_ring[(slot << 6) + lane], outp);
                    outp += NCHAN * 256;
                }
            }
        }
        lds_barrier();
    }

    // safety drain (normally empty)
    for (; nf < LLEN; ++nf) {
        const int slot = (nf + wskew + lane) & (RINGT - 1);
        __builtin_nontemporal_store(my_ring[(slot << 6) + lane], outp);
        outp += NCHAN * 256;
    }
}

} // namespace

extern "C" void kernel_launch(void* const* d_in, const int* in_sizes, int n_in,
                              void* d_out, int out_size, void* d_ws, size_t ws_size,
                              hipStream_t stream) {
    (void)in_sizes; (void)n_in; (void)d_ws; (void)ws_size; (void)out_size;
    const float* vin  = (const float*)d_in[0];   // "inputs"
    const float* dtin = (const float*)d_in[1];   // "dt"
    float* out = (float*)d_out;

    (void)hipFuncSetAttribute(reinterpret_cast<const void*>(toeplitz_scan),
                              hipFuncAttributeMaxDynamicSharedMemorySize,
                              (int)LDS_BYTES);

    toeplitz_scan<<<NCHAN, 256, LDS_BYTES, stream>>>(vin, dtin, out);
}